// Round 12
// baseline (436.178 us; speedup 1.0000x reference)
//
#include <hip/hip_runtime.h>
#include <hip/hip_bf16.h>
#include <cstdint>

#define B_SZ   4096
#define F_SZ   30
#define D_SZ   128
#define P_SZ   435
#define BM     128
#define PCH    15                     // consecutive pairs per block
#define NCHUNK 29                     // 435 / 15
#define FD     (F_SZ * D_SZ)          // 3840
#define FEMB_ELEMS (B_SZ * F_SZ * D_SZ)
#define W_ELEMS    (P_SZ * D_SZ * D_SZ)
#define GRID_MAIN  (NCHUNK * 32)      // 928 = 8 * 116

typedef __bf16 bf16x8 __attribute__((ext_vector_type(8)));
typedef float  f32x4  __attribute__((ext_vector_type(4)));
typedef unsigned short u16x8 __attribute__((ext_vector_type(8)));
typedef unsigned short u16x4 __attribute__((ext_vector_type(4)));

__device__ __forceinline__ unsigned short f2bf(float x) {
    unsigned int u = __float_as_uint(x);
    u += 0x7fffu + ((u >> 16) & 1u);
    return (unsigned short)(u >> 16);
}
__device__ __forceinline__ float bf2f(unsigned short v) {
    return __uint_as_float(((unsigned int)v) << 16);
}
__device__ __forceinline__ void gl_lds16(const void* g, void* l) {
    __builtin_amdgcn_global_load_lds(
        (const __attribute__((address_space(1))) unsigned int*)g,
        (__attribute__((address_space(3))) unsigned int*)l, 16, 0, 0);
}
#define LGKM_BAR() do { \
    asm volatile("s_waitcnt lgkmcnt(0)" ::: "memory"); \
    __builtin_amdgcn_s_barrier(); } while (0)

__global__ __launch_bounds__(256)
void cvt_bf16_kernel(const float* __restrict__ src,
                     unsigned short* __restrict__ dst, int n8) {
    int stride = gridDim.x * blockDim.x;
    for (int i = blockIdx.x * blockDim.x + threadIdx.x; i < n8; i += stride) {
        const float* s = src + (size_t)i * 8;
        f32x4 a = *reinterpret_cast<const f32x4*>(s);
        f32x4 b = *reinterpret_cast<const f32x4*>(s + 4);
        u16x8 v;
        v[0]=f2bf(a[0]); v[1]=f2bf(a[1]); v[2]=f2bf(a[2]); v[3]=f2bf(a[3]);
        v[4]=f2bf(b[0]); v[5]=f2bf(b[1]); v[6]=f2bf(b[2]); v[7]=f2bf(b[3]);
        *reinterpret_cast<u16x8*>(dst + (size_t)i * 8) = v;
    }
}

// block = (b-tile 128 rows, 15 consecutive pairs), 512 thr / 8 waves.
// Ws double-buffered via global_load_lds; dead Ws[cur] doubles as epilogue
// scratch. ALL loads of a step are issued before its NT stores, and the only
// cross-step wait is a counted vmcnt(8) -> the 8 NT stores/thread are never
// drained; the store pipe stays busy through MFMA and dump phases.
__global__ __launch_bounds__(512, 4)
void bilinear_kernel(const unsigned short* __restrict__ wsA,
                     const unsigned short* __restrict__ wsW,
                     float* __restrict__ out) {
    __shared__ unsigned short Ws[2][D_SZ * D_SZ];   // 2 x 32 KB

    // XCD swizzle: each XCD owns a 4-btile group (vj slice 3.9 MB -> L2-fit)
    const int orig  = blockIdx.x;
    const int btgrp = orig & 7;
    const int idx   = orig >> 3;          // 0..115
    const int chunk = idx % NCHUNK;
    const int btsub = idx / NCHUNK;       // 0..3
    const int m0    = (btgrp * 4 + btsub) * BM;
    const int p0    = chunk * PCH;

    int fi = 0, rem = p0;
    while (rem >= F_SZ - 1 - fi) { rem -= F_SZ - 1 - fi; ++fi; }
    int fj = fi + 1 + rem;

    const int tid  = threadIdx.x;
    const int lane = tid & 63;
    const int wave = tid >> 6;      // 0..7
    const int l16  = lane >> 4;
    const int lc   = lane & 15;

    const int wb = (wave & 3) * 32;    // b-range (32 rows) of this wave
    const int we = (wave >> 2) * 64;   // e-range (64) of this wave
    const int pass_sel = (wave & 3) >> 1;
    const int rbase    = (wave & 1) * 32;

    // readback geometry (fixed): row base 0..15, 16B chunk in row
    const int rb_r  = (tid * 16) >> 9;
    const int rb_cb = ((tid * 16) >> 4) & 31;

    u16x4 vjA[8], vjB[8];
    bf16x8 afr[2][4];

    // ---- prologue: gl_lds W(p0) -> Ws[0]; vjA = vj(fj0); afr from global ----
    {
        const unsigned short* baseW = wsW + (size_t)p0 * (D_SZ * D_SZ);
        #pragma unroll
        for (int it = 0; it < 4; ++it) {
            int r0 = it * 32 + wave * 4;
            int rl = r0 + l16;
            int cs = lc ^ (rl & 7);
            gl_lds16(baseW + rl * 128 + cs * 8, &Ws[0][r0 * 128]);
        }
        #pragma unroll
        for (int i = 0; i < 4; ++i) {
            const unsigned short* v0 =
                wsA + (size_t)(m0 + rb_r + i * 16) * FD + fj * D_SZ + rb_cb * 4;
            vjA[i]     = *reinterpret_cast<const u16x4*>(v0);
            vjA[4 + i] = *reinterpret_cast<const u16x4*>(v0 + (size_t)64 * FD);
        }
        #pragma unroll
        for (int m = 0; m < 2; ++m) {
            const unsigned short* ar =
                wsA + (size_t)(m0 + wb + m * 16 + lc) * FD + fi * D_SZ;
            #pragma unroll
            for (int kk = 0; kk < 4; ++kk)
                afr[m][kk] = *reinterpret_cast<const bf16x8*>(
                    ar + (kk * 4 + l16) * 8);
        }
    }
    __syncthreads();    // full drain once (gl_lds prologue)

    int s = 0;

#define STEP(CUR, VJC, VJN) do {                                              \
    const int p = p0 + s;                                                     \
    const bool has_next = (s + 1 < PCH);                                      \
    int fi_n = fi, fj_n = fj; bool achg = false;                              \
    if (has_next) {                                                           \
        const bool wrap = (fj == F_SZ - 1);                                   \
        fi_n = wrap ? fi + 1 : fi;                                            \
        fj_n = wrap ? fi + 2 : fj + 1;                                        \
        achg = wrap;                                                          \
        const unsigned short* baseW = wsW + (size_t)(p + 1) * (D_SZ * D_SZ);  \
        _Pragma("unroll")                                                     \
        for (int it = 0; it < 4; ++it) {                                      \
            int r0 = it * 32 + wave * 4;                                      \
            int rl = r0 + l16;                                                \
            int cs = lc ^ (rl & 7);                                           \
            gl_lds16(baseW + rl * 128 + cs * 8, &Ws[CUR ^ 1][r0 * 128]);      \
        }                                                                     \
        _Pragma("unroll")                                                     \
        for (int i = 0; i < 4; ++i) {                                         \
            const unsigned short* v0 = wsA +                                  \
                (size_t)(m0 + rb_r + i * 16) * FD + fj_n * D_SZ + rb_cb * 4;  \
            VJN[i]     = *reinterpret_cast<const u16x4*>(v0);                 \
            VJN[4 + i] = *reinterpret_cast<const u16x4*>(v0 + (size_t)64 * FD); \
        }                                                                     \
    }                                                                         \
    f32x4 acc[4][2];                                                          \
    _Pragma("unroll")                                                         \
    for (int n = 0; n < 4; ++n) {                                             \
        acc[n][0] = (f32x4)0.0f; acc[n][1] = (f32x4)0.0f;                     \
    }                                                                         \
    _Pragma("unroll")                                                         \
    for (int n = 0; n < 4; ++n) {                                             \
        int el = we + n * 16 + lc;                                            \
        _Pragma("unroll")                                                     \
        for (int kk = 0; kk < 4; ++kk) {                                      \
            bf16x8 wfr = *reinterpret_cast<const bf16x8*>(                    \
                &Ws[CUR][el * 128 + (((kk * 4 + l16) ^ (el & 7)) * 8)]);      \
            acc[n][0] = __builtin_amdgcn_mfma_f32_16x16x32_bf16(              \
                wfr, afr[0][kk], acc[n][0], 0, 0, 0);                         \
            acc[n][1] = __builtin_amdgcn_mfma_f32_16x16x32_bf16(              \
                wfr, afr[1][kk], acc[n][1], 0, 0, 0);                         \
        }                                                                     \
    }                                                                         \
    LGKM_BAR();                                                               \
    float* scrf = reinterpret_cast<float*>(&Ws[CUR][0]);                      \
    if (pass_sel == 0) {                                                      \
        _Pragma("unroll")                                                     \
        for (int m = 0; m < 2; ++m) {                                         \
            int r = rbase + m * 16 + lc;                                      \
            _Pragma("unroll")                                                 \
            for (int n = 0; n < 4; ++n) {                                     \
                int c = (we >> 2) + n * 4 + l16;                              \
                *reinterpret_cast<f32x4*>(                                    \
                    &scrf[(r * 32 + (c ^ (r & 7))) * 4]) = acc[n][m];         \
            }                                                                 \
        }                                                                     \
    }                                                                         \
    LGKM_BAR();                                                               \
    _Pragma("unroll")                                                         \
    for (int i = 0; i < 4; ++i) {                                             \
        int r = rb_r + i * 16;                                                \
        f32x4 v = *reinterpret_cast<const f32x4*>(                            \
            &scrf[(r * 32 + (rb_cb ^ (r & 7))) * 4]);                         \
        f32x4 o;                                                              \
        o[0] = v[0] * bf2f(VJC[i][0]);                                        \
        o[1] = v[1] * bf2f(VJC[i][1]);                                        \
        o[2] = v[2] * bf2f(VJC[i][2]);                                        \
        o[3] = v[3] * bf2f(VJC[i][3]);                                        \
        __builtin_nontemporal_store(o, reinterpret_cast<f32x4*>(              \
            out + ((size_t)(m0 + r) * P_SZ + p) * D_SZ + rb_cb * 4));         \
    }                                                                         \
    LGKM_BAR();                                                               \
    if (pass_sel == 1) {                                                      \
        _Pragma("unroll")                                                     \
        for (int m = 0; m < 2; ++m) {                                         \
            int r = rbase + m * 16 + lc;                                      \
            _Pragma("unroll")                                                 \
            for (int n = 0; n < 4; ++n) {                                     \
                int c = (we >> 2) + n * 4 + l16;                              \
                *reinterpret_cast<f32x4*>(                                    \
                    &scrf[(r * 32 + (c ^ (r & 7))) * 4]) = acc[n][m];         \
            }                                                                 \
        }                                                                     \
    }                                                                         \
    LGKM_BAR();                                                               \
    _Pragma("unroll")                                                         \
    for (int i = 0; i < 4; ++i) {                                             \
        int r = rb_r + i * 16;                                                \
        f32x4 v = *reinterpret_cast<const f32x4*>(                            \
            &scrf[(r * 32 + (rb_cb ^ (r & 7))) * 4]);                         \
        f32x4 o;                                                              \
        o[0] = v[0] * bf2f(VJC[4 + i][0]);                                    \
        o[1] = v[1] * bf2f(VJC[4 + i][1]);                                    \
        o[2] = v[2] * bf2f(VJC[4 + i][2]);                                    \
        o[3] = v[3] * bf2f(VJC[4 + i][3]);                                    \
        __builtin_nontemporal_store(o, reinterpret_cast<f32x4*>(              \
            out + ((size_t)(m0 + 64 + r) * P_SZ + p) * D_SZ + rb_cb * 4));    \
    }                                                                         \
    if (has_next) {                                                           \
        if (achg) {                                                           \
            _Pragma("unroll")                                                 \
            for (int m = 0; m < 2; ++m) {                                     \
                const unsigned short* ar =                                    \
                    wsA + (size_t)(m0 + wb + m * 16 + lc) * FD + fi_n * D_SZ; \
                _Pragma("unroll")                                             \
                for (int kk = 0; kk < 4; ++kk)                                \
                    afr[m][kk] = *reinterpret_cast<const bf16x8*>(            \
                        ar + (kk * 4 + l16) * 8);                             \
            }                                                                 \
        }                                                                     \
        asm volatile("s_waitcnt vmcnt(8)" ::: "memory");                      \
        __builtin_amdgcn_s_barrier();                                         \
    }                                                                         \
    fi = fi_n; fj = fj_n;                                                     \
} while (0)

    while (true) {
        STEP(0, vjA, vjB);
        if (++s >= PCH) break;
        STEP(1, vjB, vjA);
        if (++s >= PCH) break;
    }
#undef STEP
}

extern "C" void kernel_launch(void* const* d_in, const int* in_sizes, int n_in,
                              void* d_out, int out_size, void* d_ws, size_t ws_size,
                              hipStream_t stream) {
    const float* femb = (const float*)d_in[0];
    const float* W    = (const float*)d_in[1];
    float* out        = (float*)d_out;

    unsigned short* wsA = (unsigned short*)d_ws;
    unsigned short* wsW = wsA + FEMB_ELEMS;

    hipLaunchKernelGGL(cvt_bf16_kernel, dim3(2048), dim3(256), 0, stream,
                       femb, wsA, FEMB_ELEMS / 8);
    hipLaunchKernelGGL(cvt_bf16_kernel, dim3(2048), dim3(256), 0, stream,
                       W, wsW, W_ELEMS / 8);
    hipLaunchKernelGGL(bilinear_kernel, dim3(GRID_MAIN), dim3(512), 0, stream,
                       wsA, wsW, out);
}

// Round 13
// 249.578 us; speedup vs baseline: 1.7477x; 1.7477x over previous
//
#include <hip/hip_runtime.h>
#include <hip/hip_bf16.h>
#include <cstdint>

#define B_SZ   4096
#define F_SZ   30
#define D_SZ   128
#define P_SZ   435
#define BM     128
#define PCH    15                     // consecutive pairs per block
#define NCHUNK 29                     // 435 / 15
#define FD     (F_SZ * D_SZ)          // 3840
#define FEMB_ELEMS (B_SZ * F_SZ * D_SZ)
#define W_ELEMS    (P_SZ * D_SZ * D_SZ)
#define GRID_MAIN  (NCHUNK * 32)      // 928 = 8 * 116

typedef __bf16 bf16x8 __attribute__((ext_vector_type(8)));
typedef float  f32x4  __attribute__((ext_vector_type(4)));
typedef unsigned short u16x8 __attribute__((ext_vector_type(8)));
typedef unsigned short u16x4 __attribute__((ext_vector_type(4)));

__device__ __forceinline__ unsigned short f2bf(float x) {
    unsigned int u = __float_as_uint(x);
    u += 0x7fffu + ((u >> 16) & 1u);
    return (unsigned short)(u >> 16);
}
__device__ __forceinline__ float bf2f(unsigned short v) {
    return __uint_as_float(((unsigned int)v) << 16);
}
__device__ __forceinline__ void gl_lds16(const void* g, void* l) {
    __builtin_amdgcn_global_load_lds(
        (const __attribute__((address_space(1))) unsigned int*)g,
        (__attribute__((address_space(3))) unsigned int*)l, 16, 0, 0);
}
#define LGKM_BAR() do { \
    asm volatile("s_waitcnt lgkmcnt(0)" ::: "memory"); \
    __builtin_amdgcn_s_barrier(); } while (0)

__global__ __launch_bounds__(256)
void cvt_bf16_kernel(const float* __restrict__ src,
                     unsigned short* __restrict__ dst, int n8) {
    int stride = gridDim.x * blockDim.x;
    for (int i = blockIdx.x * blockDim.x + threadIdx.x; i < n8; i += stride) {
        const float* s = src + (size_t)i * 8;
        f32x4 a = *reinterpret_cast<const f32x4*>(s);
        f32x4 b = *reinterpret_cast<const f32x4*>(s + 4);
        u16x8 v;
        v[0]=f2bf(a[0]); v[1]=f2bf(a[1]); v[2]=f2bf(a[2]); v[3]=f2bf(a[3]);
        v[4]=f2bf(b[0]); v[5]=f2bf(b[1]); v[6]=f2bf(b[2]); v[7]=f2bf(b[3]);
        *reinterpret_cast<u16x8*>(dst + (size_t)i * 8) = v;
    }
}

// block = (b-tile 128 rows, 15 consecutive pairs), 512 thr / 8 waves.
// Ws double-buffered via global_load_lds; dead Ws[cur] doubles as epilogue
// scratch. ALL loads of a step are issued before its NT stores; the only
// cross-step wait is a counted vmcnt(8) -> the 8 NT stores/thread are never
// drained. launch_bounds(512,2): VGPR cap 256 (R12's cap-128 spilled).
__global__ __launch_bounds__(512, 2)
void bilinear_kernel(const unsigned short* __restrict__ wsA,
                     const unsigned short* __restrict__ wsW,
                     float* __restrict__ out) {
    __shared__ unsigned short Ws[2][D_SZ * D_SZ];   // 2 x 32 KB

    // XCD swizzle: each XCD owns a 4-btile group (vj slice 3.9 MB -> L2-fit)
    const int orig  = blockIdx.x;
    const int btgrp = orig & 7;
    const int idx   = orig >> 3;          // 0..115
    const int chunk = idx % NCHUNK;
    const int btsub = idx / NCHUNK;       // 0..3
    const int m0    = (btgrp * 4 + btsub) * BM;
    const int p0    = chunk * PCH;

    int fi = 0, rem = p0;
    while (rem >= F_SZ - 1 - fi) { rem -= F_SZ - 1 - fi; ++fi; }
    int fj = fi + 1 + rem;

    const int tid  = threadIdx.x;
    const int lane = tid & 63;
    const int wave = tid >> 6;      // 0..7
    const int l16  = lane >> 4;
    const int lc   = lane & 15;

    const int wb = (wave & 3) * 32;    // b-range (32 rows) of this wave
    const int we = (wave >> 2) * 64;   // e-range (64) of this wave
    const int pass_sel = (wave & 3) >> 1;
    const int rbase    = (wave & 1) * 32;

    // readback geometry (fixed): row base 0..15, 16B chunk in row
    const int rb_r  = (tid * 16) >> 9;
    const int rb_cb = ((tid * 16) >> 4) & 31;

    u16x4 vjA[8], vjB[8];
    bf16x8 afr[2][4];

    // ---- prologue: gl_lds W(p0) -> Ws[0]; vjA = vj(fj0); afr from global ----
    {
        const unsigned short* baseW = wsW + (size_t)p0 * (D_SZ * D_SZ);
        #pragma unroll
        for (int it = 0; it < 4; ++it) {
            int r0 = it * 32 + wave * 4;
            int rl = r0 + l16;
            int cs = lc ^ (rl & 7);
            gl_lds16(baseW + rl * 128 + cs * 8, &Ws[0][r0 * 128]);
        }
        #pragma unroll
        for (int i = 0; i < 4; ++i) {
            const unsigned short* v0 =
                wsA + (size_t)(m0 + rb_r + i * 16) * FD + fj * D_SZ + rb_cb * 4;
            vjA[i]     = *reinterpret_cast<const u16x4*>(v0);
            vjA[4 + i] = *reinterpret_cast<const u16x4*>(v0 + (size_t)64 * FD);
        }
        #pragma unroll
        for (int m = 0; m < 2; ++m) {
            const unsigned short* ar =
                wsA + (size_t)(m0 + wb + m * 16 + lc) * FD + fi * D_SZ;
            #pragma unroll
            for (int kk = 0; kk < 4; ++kk)
                afr[m][kk] = *reinterpret_cast<const bf16x8*>(
                    ar + (kk * 4 + l16) * 8);
        }
    }
    __syncthreads();    // full drain once (gl_lds prologue)

    int s = 0;

#define STEP(CUR, VJC, VJN) do {                                              \
    const int p = p0 + s;                                                     \
    const bool has_next = (s + 1 < PCH);                                      \
    int fi_n = fi, fj_n = fj; bool achg = false;                              \
    if (has_next) {                                                           \
        const bool wrap = (fj == F_SZ - 1);                                   \
        fi_n = wrap ? fi + 1 : fi;                                            \
        fj_n = wrap ? fi + 2 : fj + 1;                                        \
        achg = wrap;                                                          \
        const unsigned short* baseW = wsW + (size_t)(p + 1) * (D_SZ * D_SZ);  \
        _Pragma("unroll")                                                     \
        for (int it = 0; it < 4; ++it) {                                      \
            int r0 = it * 32 + wave * 4;                                      \
            int rl = r0 + l16;                                                \
            int cs = lc ^ (rl & 7);                                           \
            gl_lds16(baseW + rl * 128 + cs * 8, &Ws[CUR ^ 1][r0 * 128]);      \
        }                                                                     \
        _Pragma("unroll")                                                     \
        for (int i = 0; i < 4; ++i) {                                         \
            const unsigned short* v0 = wsA +                                  \
                (size_t)(m0 + rb_r + i * 16) * FD + fj_n * D_SZ + rb_cb * 4;  \
            VJN[i]     = *reinterpret_cast<const u16x4*>(v0);                 \
            VJN[4 + i] = *reinterpret_cast<const u16x4*>(v0 + (size_t)64 * FD); \
        }                                                                     \
    }                                                                         \
    f32x4 acc[4][2];                                                          \
    _Pragma("unroll")                                                         \
    for (int n = 0; n < 4; ++n) {                                             \
        acc[n][0] = (f32x4)0.0f; acc[n][1] = (f32x4)0.0f;                     \
    }                                                                         \
    _Pragma("unroll")                                                         \
    for (int n = 0; n < 4; ++n) {                                             \
        int el = we + n * 16 + lc;                                            \
        _Pragma("unroll")                                                     \
        for (int kk = 0; kk < 4; ++kk) {                                      \
            bf16x8 wfr = *reinterpret_cast<const bf16x8*>(                    \
                &Ws[CUR][el * 128 + (((kk * 4 + l16) ^ (el & 7)) * 8)]);      \
            acc[n][0] = __builtin_amdgcn_mfma_f32_16x16x32_bf16(              \
                wfr, afr[0][kk], acc[n][0], 0, 0, 0);                         \
            acc[n][1] = __builtin_amdgcn_mfma_f32_16x16x32_bf16(              \
                wfr, afr[1][kk], acc[n][1], 0, 0, 0);                         \
        }                                                                     \
    }                                                                         \
    LGKM_BAR();                                                               \
    float* scrf = reinterpret_cast<float*>(&Ws[CUR][0]);                      \
    if (pass_sel == 0) {                                                      \
        _Pragma("unroll")                                                     \
        for (int m = 0; m < 2; ++m) {                                         \
            int r = rbase + m * 16 + lc;                                      \
            _Pragma("unroll")                                                 \
            for (int n = 0; n < 4; ++n) {                                     \
                int c = (we >> 2) + n * 4 + l16;                              \
                *reinterpret_cast<f32x4*>(                                    \
                    &scrf[(r * 32 + (c ^ (r & 7))) * 4]) = acc[n][m];         \
            }                                                                 \
        }                                                                     \
    }                                                                         \
    LGKM_BAR();                                                               \
    _Pragma("unroll")                                                         \
    for (int i = 0; i < 4; ++i) {                                             \
        int r = rb_r + i * 16;                                                \
        f32x4 v = *reinterpret_cast<const f32x4*>(                            \
            &scrf[(r * 32 + (rb_cb ^ (r & 7))) * 4]);                         \
        f32x4 o;                                                              \
        o[0] = v[0] * bf2f(VJC[i][0]);                                        \
        o[1] = v[1] * bf2f(VJC[i][1]);                                        \
        o[2] = v[2] * bf2f(VJC[i][2]);                                        \
        o[3] = v[3] * bf2f(VJC[i][3]);                                        \
        __builtin_nontemporal_store(o, reinterpret_cast<f32x4*>(              \
            out + ((size_t)(m0 + r) * P_SZ + p) * D_SZ + rb_cb * 4));         \
    }                                                                         \
    LGKM_BAR();                                                               \
    if (pass_sel == 1) {                                                      \
        _Pragma("unroll")                                                     \
        for (int m = 0; m < 2; ++m) {                                         \
            int r = rbase + m * 16 + lc;                                      \
            _Pragma("unroll")                                                 \
            for (int n = 0; n < 4; ++n) {                                     \
                int c = (we >> 2) + n * 4 + l16;                              \
                *reinterpret_cast<f32x4*>(                                    \
                    &scrf[(r * 32 + (c ^ (r & 7))) * 4]) = acc[n][m];         \
            }                                                                 \
        }                                                                     \
    }                                                                         \
    LGKM_BAR();                                                               \
    _Pragma("unroll")                                                         \
    for (int i = 0; i < 4; ++i) {                                             \
        int r = rb_r + i * 16;                                                \
        f32x4 v = *reinterpret_cast<const f32x4*>(                            \
            &scrf[(r * 32 + (rb_cb ^ (r & 7))) * 4]);                         \
        f32x4 o;                                                              \
        o[0] = v[0] * bf2f(VJC[4 + i][0]);                                    \
        o[1] = v[1] * bf2f(VJC[4 + i][1]);                                    \
        o[2] = v[2] * bf2f(VJC[4 + i][2]);                                    \
        o[3] = v[3] * bf2f(VJC[4 + i][3]);                                    \
        __builtin_nontemporal_store(o, reinterpret_cast<f32x4*>(              \
            out + ((size_t)(m0 + 64 + r) * P_SZ + p) * D_SZ + rb_cb * 4));    \
    }                                                                         \
    if (has_next) {                                                           \
        if (achg) {                                                           \
            _Pragma("unroll")                                                 \
            for (int m = 0; m < 2; ++m) {                                     \
                const unsigned short* ar =                                    \
                    wsA + (size_t)(m0 + wb + m * 16 + lc) * FD + fi_n * D_SZ; \
                _Pragma("unroll")                                             \
                for (int kk = 0; kk < 4; ++kk)                                \
                    afr[m][kk] = *reinterpret_cast<const bf16x8*>(            \
                        ar + (kk * 4 + l16) * 8);                             \
            }                                                                 \
        }                                                                     \
        asm volatile("s_waitcnt vmcnt(8)" ::: "memory");                      \
        __builtin_amdgcn_s_barrier();                                         \
    }                                                                         \
    fi = fi_n; fj = fj_n;                                                     \
} while (0)

    while (true) {
        STEP(0, vjA, vjB);
        if (++s >= PCH) break;
        STEP(1, vjB, vjA);
        if (++s >= PCH) break;
    }
#undef STEP
}

extern "C" void kernel_launch(void* const* d_in, const int* in_sizes, int n_in,
                              void* d_out, int out_size, void* d_ws, size_t ws_size,
                              hipStream_t stream) {
    const float* femb = (const float*)d_in[0];
    const float* W    = (const float*)d_in[1];
    float* out        = (float*)d_out;

    unsigned short* wsA = (unsigned short*)d_ws;
    unsigned short* wsW = wsA + FEMB_ELEMS;

    hipLaunchKernelGGL(cvt_bf16_kernel, dim3(2048), dim3(256), 0, stream,
                       femb, wsA, FEMB_ELEMS / 8);
    hipLaunchKernelGGL(cvt_bf16_kernel, dim3(2048), dim3(256), 0, stream,
                       W, wsW, W_ELEMS / 8);
    hipLaunchKernelGGL(bilinear_kernel, dim3(GRID_MAIN), dim3(512), 0, stream,
                       wsA, wsW, out);
}

// Round 15
// 244.779 us; speedup vs baseline: 1.7819x; 1.0196x over previous
//
#include <hip/hip_runtime.h>
#include <hip/hip_bf16.h>
#include <cstdint>

#define B_SZ   4096
#define F_SZ   30
#define D_SZ   128
#define P_SZ   435
#define BM     128
#define PCH    15                     // consecutive pairs per block
#define NCHUNK 29                     // 435 / 15
#define FD     (F_SZ * D_SZ)          // 3840
#define FEMB_ELEMS (B_SZ * F_SZ * D_SZ)
#define W_ELEMS    (P_SZ * D_SZ * D_SZ)
#define GRID_MAIN  (NCHUNK * 32)      // 928 = 8 * 116

typedef __bf16 bf16x8 __attribute__((ext_vector_type(8)));
typedef float  f32x4  __attribute__((ext_vector_type(4)));
typedef unsigned short u16x8 __attribute__((ext_vector_type(8)));
typedef unsigned short u16x4 __attribute__((ext_vector_type(4)));

__device__ __forceinline__ unsigned short f2bf(float x) {
    unsigned int u = __float_as_uint(x);
    u += 0x7fffu + ((u >> 16) & 1u);
    return (unsigned short)(u >> 16);
}
__device__ __forceinline__ float bf2f(unsigned short v) {
    return __uint_as_float(((unsigned int)v) << 16);
}
__device__ __forceinline__ void gl_lds16(const void* g, void* l) {
    __builtin_amdgcn_global_load_lds(
        (const __attribute__((address_space(1))) unsigned int*)g,
        (__attribute__((address_space(3))) unsigned int*)l, 16, 0, 0);
}
#define LGKM_BAR() do { \
    asm volatile("s_waitcnt lgkmcnt(0)" ::: "memory"); \
    __builtin_amdgcn_s_barrier(); } while (0)
// Intra-wave LDS phase fence: "memory" pins compiler ordering of the DS ops
// (cross-lane communication is invisible to per-thread alias analysis);
// lgkmcnt(0) is ~free since DS completes in-order per wave.
#define WAVE_FENCE() asm volatile("s_waitcnt lgkmcnt(0)" ::: "memory")

__global__ __launch_bounds__(256)
void cvt_bf16_kernel(const float* __restrict__ src,
                     unsigned short* __restrict__ dst, int n8) {
    int stride = gridDim.x * blockDim.x;
    for (int i = blockIdx.x * blockDim.x + threadIdx.x; i < n8; i += stride) {
        const float* s = src + (size_t)i * 8;
        f32x4 a = *reinterpret_cast<const f32x4*>(s);
        f32x4 b = *reinterpret_cast<const f32x4*>(s + 4);
        u16x8 v;
        v[0]=f2bf(a[0]); v[1]=f2bf(a[1]); v[2]=f2bf(a[2]); v[3]=f2bf(a[3]);
        v[4]=f2bf(b[0]); v[5]=f2bf(b[1]); v[6]=f2bf(b[2]); v[7]=f2bf(b[3]);
        *reinterpret_cast<u16x8*>(dst + (size_t)i * 8) = v;
    }
}

// block = (b-tile 128 rows, 15 consecutive pairs), 512 thr / 8 waves.
// Each wave owns 16 b-rows x FULL 128 e -> epilogue transpose uses a
// wave-PRIVATE 4KB slice of the dead Ws[cur]; phases inside the epilogue are
// ordered by WAVE_FENCE (compiler fence + lgkm drain), not block barriers.
// 2 block barriers/step.
__global__ __launch_bounds__(512, 2)
void bilinear_kernel(const unsigned short* __restrict__ wsA,
                     const unsigned short* __restrict__ wsW,
                     float* __restrict__ out) {
    __shared__ unsigned short Ws[2][D_SZ * D_SZ];   // 2 x 32 KB

    // XCD swizzle: each XCD owns a 4-btile group (vj slice 3.9 MB -> L2-fit)
    const int orig  = blockIdx.x;
    const int btgrp = orig & 7;
    const int idx   = orig >> 3;          // 0..115
    const int chunk = idx % NCHUNK;
    const int btsub = idx / NCHUNK;       // 0..3
    const int m0    = (btgrp * 4 + btsub) * BM;
    const int p0    = chunk * PCH;

    int fi = 0, rem = p0;
    while (rem >= F_SZ - 1 - fi) { rem -= F_SZ - 1 - fi; ++fi; }
    int fj = fi + 1 + rem;

    const int tid  = threadIdx.x;
    const int lane = tid & 63;
    const int wave = tid >> 6;      // 0..7
    const int l16  = lane >> 4;
    const int lc   = lane & 15;
    const int wrow = wave * 16;     // this wave's b-sub-tile base

    // readback geometry (per lane): row-in-half + 16B chunk
    const int rb_rl = lane >> 5;          // +2 per iter
    const int rb_c  = lane & 31;

    bf16x8 afr[4];

    // ---- prologue: gl_lds W(p0) -> Ws[0]; afr(fi) from global ----
    {
        const unsigned short* baseW = wsW + (size_t)p0 * (D_SZ * D_SZ);
        #pragma unroll
        for (int it = 0; it < 4; ++it) {
            int r0 = it * 32 + wave * 4;
            int rl = r0 + l16;
            int cs = lc ^ (rl & 7);
            gl_lds16(baseW + rl * 128 + cs * 8, &Ws[0][r0 * 128]);
        }
        const unsigned short* ar =
            wsA + (size_t)(m0 + wrow + lc) * FD + fi * D_SZ;
        #pragma unroll
        for (int kk = 0; kk < 4; ++kk)
            afr[kk] = *reinterpret_cast<const bf16x8*>(ar + (kk * 4 + l16) * 8);
    }
    __syncthreads();    // full drain once (gl_lds prologue)

    int s = 0;

#define STEP(CUR) do {                                                        \
    const int p = p0 + s;                                                     \
    const bool has_next = (s + 1 < PCH);                                      \
    int fi_n = fi, fj_n = fj; bool achg = false;                              \
    if (has_next) {                                                           \
        const bool wrap = (fj == F_SZ - 1);                                   \
        fi_n = wrap ? fi + 1 : fi;                                            \
        fj_n = wrap ? fi + 2 : fj + 1;                                        \
        achg = wrap;                                                          \
        const unsigned short* baseW = wsW + (size_t)(p + 1) * (D_SZ * D_SZ);  \
        _Pragma("unroll")                                                     \
        for (int it = 0; it < 4; ++it) {                                      \
            int r0 = it * 32 + wave * 4;                                      \
            int rl = r0 + l16;                                                \
            int cs = lc ^ (rl & 7);                                           \
            gl_lds16(baseW + rl * 128 + cs * 8, &Ws[CUR ^ 1][r0 * 128]);      \
        }                                                                     \
    }                                                                         \
    /* vj for CURRENT step: wave's 16 rows x 128 e, contiguous per row */     \
    u16x4 vjreg[8];                                                           \
    _Pragma("unroll")                                                         \
    for (int h = 0; h < 2; ++h)                                               \
        _Pragma("unroll")                                                     \
        for (int i = 0; i < 4; ++i) {                                         \
            int b = m0 + wrow + h * 8 + i * 2 + rb_rl;                        \
            vjreg[h * 4 + i] = *reinterpret_cast<const u16x4*>(               \
                wsA + (size_t)b * FD + fj * D_SZ + rb_c * 4);                 \
        }                                                                     \
    f32x4 acc[8];                                                             \
    _Pragma("unroll")                                                         \
    for (int n = 0; n < 8; ++n) acc[n] = (f32x4)0.0f;                         \
    _Pragma("unroll")                                                         \
    for (int n = 0; n < 8; ++n) {                                             \
        int el = n * 16 + lc;                                                 \
        _Pragma("unroll")                                                     \
        for (int kk = 0; kk < 4; ++kk) {                                      \
            bf16x8 wfr = *reinterpret_cast<const bf16x8*>(                    \
                &Ws[CUR][el * 128 + (((kk * 4 + l16) ^ (el & 7)) * 8)]);      \
            acc[n] = __builtin_amdgcn_mfma_f32_16x16x32_bf16(                 \
                wfr, afr[kk], acc[n], 0, 0, 0);                               \
        }                                                                     \
    }                                                                         \
    LGKM_BAR();   /* all waves done reading Ws[CUR]; it becomes scratch */    \
    {                                                                         \
        float* swav = reinterpret_cast<float*>(&Ws[CUR][0]) + wave * 1024;    \
        _Pragma("unroll")                                                     \
        for (int h = 0; h < 2; ++h) {                                         \
            /* dump: half the lanes write their 8 rows of this b-half */      \
            if ((lc >> 3) == h) {                                             \
                int rl = lc & 7;                                              \
                _Pragma("unroll")                                             \
                for (int n = 0; n < 8; ++n) {                                 \
                    int c = n * 4 + l16;                                      \
                    *reinterpret_cast<f32x4*>(                                \
                        &swav[(rl * 32 + (c ^ rl)) * 4]) = acc[n];            \
                }                                                             \
            }                                                                 \
            WAVE_FENCE();   /* dump visible before cross-lane readback */     \
            /* readback: 2 rows x 512B contiguous per instr */                \
            _Pragma("unroll")                                                 \
            for (int i = 0; i < 4; ++i) {                                     \
                int rl = i * 2 + rb_rl;                                       \
                f32x4 v = *reinterpret_cast<const f32x4*>(                    \
                    &swav[(rl * 32 + (rb_c ^ rl)) * 4]);                      \
                int b = m0 + wrow + h * 8 + rl;                               \
                u16x4 vjb = vjreg[h * 4 + i];                                 \
                f32x4 o;                                                      \
                o[0] = v[0] * bf2f(vjb[0]);                                   \
                o[1] = v[1] * bf2f(vjb[1]);                                   \
                o[2] = v[2] * bf2f(vjb[2]);                                   \
                o[3] = v[3] * bf2f(vjb[3]);                                   \
                __builtin_nontemporal_store(o, reinterpret_cast<f32x4*>(      \
                    out + ((size_t)b * P_SZ + p) * D_SZ + rb_c * 4));         \
            }                                                                 \
            WAVE_FENCE();   /* readback done before next-h dump overwrites */ \
        }                                                                     \
    }                                                                         \
    if (has_next) {                                                           \
        if (achg) {                                                           \
            const unsigned short* ar =                                        \
                wsA + (size_t)(m0 + wrow + lc) * FD + fi_n * D_SZ;            \
            _Pragma("unroll")                                                 \
            for (int kk = 0; kk < 4; ++kk)                                    \
                afr[kk] = *reinterpret_cast<const bf16x8*>(                   \
                    ar + (kk * 4 + l16) * 8);                                 \
        }                                                                     \
        /* retire gl_lds+vj (oldest), keep NT stores in flight; lgkm(0) so */ \
        /* every wave's scratch ops are done before next gl_lds lands     */  \
        asm volatile("s_waitcnt vmcnt(8) lgkmcnt(0)" ::: "memory");           \
        __builtin_amdgcn_s_barrier();                                         \
    }                                                                         \
    fi = fi_n; fj = fj_n;                                                     \
} while (0)

    while (true) {
        STEP(0);
        if (++s >= PCH) break;
        STEP(1);
        if (++s >= PCH) break;
    }
#undef STEP
}

extern "C" void kernel_launch(void* const* d_in, const int* in_sizes, int n_in,
                              void* d_out, int out_size, void* d_ws, size_t ws_size,
                              hipStream_t stream) {
    const float* femb = (const float*)d_in[0];
    const float* W    = (const float*)d_in[1];
    float* out        = (float*)d_out;

    unsigned short* wsA = (unsigned short*)d_ws;
    unsigned short* wsW = wsA + FEMB_ELEMS;

    hipLaunchKernelGGL(cvt_bf16_kernel, dim3(2048), dim3(256), 0, stream,
                       femb, wsA, FEMB_ELEMS / 8);
    hipLaunchKernelGGL(cvt_bf16_kernel, dim3(2048), dim3(256), 0, stream,
                       W, wsW, W_ELEMS / 8);
    hipLaunchKernelGGL(bilinear_kernel, dim3(GRID_MAIN), dim3(512), 0, stream,
                       wsA, wsW, out);
}

// Round 16
// 213.137 us; speedup vs baseline: 2.0465x; 1.1485x over previous
//
#include <hip/hip_runtime.h>
#include <hip/hip_bf16.h>
#include <cstdint>

#define B_SZ   4096
#define F_SZ   30
#define D_SZ   128
#define P_SZ   435
#define BM     128
#define PCH    15                     // consecutive pairs per block
#define NCHUNK 29                     // 435 / 15
#define FD     (F_SZ * D_SZ)          // 3840
#define FEMB_ELEMS (B_SZ * F_SZ * D_SZ)
#define W_ELEMS    (P_SZ * D_SZ * D_SZ)
#define GRID_MAIN  (NCHUNK * 32)      // 928 = 8 * 116

typedef __bf16 bf16x8 __attribute__((ext_vector_type(8)));
typedef float  f32x4  __attribute__((ext_vector_type(4)));
typedef unsigned short u16x8 __attribute__((ext_vector_type(8)));
typedef unsigned short u16x4 __attribute__((ext_vector_type(4)));

__device__ __forceinline__ unsigned short f2bf(float x) {
    unsigned int u = __float_as_uint(x);
    u += 0x7fffu + ((u >> 16) & 1u);
    return (unsigned short)(u >> 16);
}
__device__ __forceinline__ float bf2f(unsigned short v) {
    return __uint_as_float(((unsigned int)v) << 16);
}
__device__ __forceinline__ void gl_lds16(const void* g, void* l) {
    __builtin_amdgcn_global_load_lds(
        (const __attribute__((address_space(1))) unsigned int*)g,
        (__attribute__((address_space(3))) unsigned int*)l, 16, 0, 0);
}
#define LGKM_BAR() do { \
    asm volatile("s_waitcnt lgkmcnt(0)" ::: "memory"); \
    __builtin_amdgcn_s_barrier(); } while (0)
// Intra-wave LDS phase fence: "memory" pins compiler ordering of the DS ops
// (cross-lane communication is invisible to per-thread alias analysis);
// lgkmcnt(0) is ~free since DS completes in-order per wave.
#define WAVE_FENCE() asm volatile("s_waitcnt lgkmcnt(0)" ::: "memory")

__global__ __launch_bounds__(256)
void cvt_bf16_kernel(const float* __restrict__ src,
                     unsigned short* __restrict__ dst, int n8) {
    int stride = gridDim.x * blockDim.x;
    for (int i = blockIdx.x * blockDim.x + threadIdx.x; i < n8; i += stride) {
        const float* s = src + (size_t)i * 8;
        f32x4 a = *reinterpret_cast<const f32x4*>(s);
        f32x4 b = *reinterpret_cast<const f32x4*>(s + 4);
        u16x8 v;
        v[0]=f2bf(a[0]); v[1]=f2bf(a[1]); v[2]=f2bf(a[2]); v[3]=f2bf(a[3]);
        v[4]=f2bf(b[0]); v[5]=f2bf(b[1]); v[6]=f2bf(b[2]); v[7]=f2bf(b[3]);
        *reinterpret_cast<u16x8*>(dst + (size_t)i * 8) = v;
    }
}

// block = (b-tile 128 rows, 15 consecutive pairs), 512 thr / 8 waves.
// R16 A/B vs R15 (one line): idx decomposition swapped so the 4 blocks on an
// XCD that share a W-chunk are ADJACENT in dispatch -> concurrent -> W pair
// fetched once per XCD from L3, reused 4x from L2 (W fabric 445 -> ~111 MB).
__global__ __launch_bounds__(512, 2)
void bilinear_kernel(const unsigned short* __restrict__ wsA,
                     const unsigned short* __restrict__ wsW,
                     float* __restrict__ out) {
    __shared__ unsigned short Ws[2][D_SZ * D_SZ];   // 2 x 32 KB

    // XCD swizzle: each XCD owns a 4-btile group (vj slice 3.9 MB -> L2-fit)
    const int orig  = blockIdx.x;
    const int btgrp = orig & 7;
    const int idx   = orig >> 3;          // 0..115
    const int btsub = idx & 3;            // 0..3  (same-chunk blocks adjacent)
    const int chunk = idx >> 2;           // 0..28
    const int m0    = (btgrp * 4 + btsub) * BM;
    const int p0    = chunk * PCH;

    int fi = 0, rem = p0;
    while (rem >= F_SZ - 1 - fi) { rem -= F_SZ - 1 - fi; ++fi; }
    int fj = fi + 1 + rem;

    const int tid  = threadIdx.x;
    const int lane = tid & 63;
    const int wave = tid >> 6;      // 0..7
    const int l16  = lane >> 4;
    const int lc   = lane & 15;
    const int wrow = wave * 16;     // this wave's b-sub-tile base

    // readback geometry (per lane): row-in-half + 16B chunk
    const int rb_rl = lane >> 5;          // +2 per iter
    const int rb_c  = lane & 31;

    bf16x8 afr[4];

    // ---- prologue: gl_lds W(p0) -> Ws[0]; afr(fi) from global ----
    {
        const unsigned short* baseW = wsW + (size_t)p0 * (D_SZ * D_SZ);
        #pragma unroll
        for (int it = 0; it < 4; ++it) {
            int r0 = it * 32 + wave * 4;
            int rl = r0 + l16;
            int cs = lc ^ (rl & 7);
            gl_lds16(baseW + rl * 128 + cs * 8, &Ws[0][r0 * 128]);
        }
        const unsigned short* ar =
            wsA + (size_t)(m0 + wrow + lc) * FD + fi * D_SZ;
        #pragma unroll
        for (int kk = 0; kk < 4; ++kk)
            afr[kk] = *reinterpret_cast<const bf16x8*>(ar + (kk * 4 + l16) * 8);
    }
    __syncthreads();    // full drain once (gl_lds prologue)

    int s = 0;

#define STEP(CUR) do {                                                        \
    const int p = p0 + s;                                                     \
    const bool has_next = (s + 1 < PCH);                                      \
    int fi_n = fi, fj_n = fj; bool achg = false;                              \
    if (has_next) {                                                           \
        const bool wrap = (fj == F_SZ - 1);                                   \
        fi_n = wrap ? fi + 1 : fi;                                            \
        fj_n = wrap ? fi + 2 : fj + 1;                                        \
        achg = wrap;                                                          \
        const unsigned short* baseW = wsW + (size_t)(p + 1) * (D_SZ * D_SZ);  \
        _Pragma("unroll")                                                     \
        for (int it = 0; it < 4; ++it) {                                      \
            int r0 = it * 32 + wave * 4;                                      \
            int rl = r0 + l16;                                                \
            int cs = lc ^ (rl & 7);                                           \
            gl_lds16(baseW + rl * 128 + cs * 8, &Ws[CUR ^ 1][r0 * 128]);      \
        }                                                                     \
    }                                                                         \
    /* vj for CURRENT step: wave's 16 rows x 128 e, contiguous per row */     \
    u16x4 vjreg[8];                                                           \
    _Pragma("unroll")                                                         \
    for (int h = 0; h < 2; ++h)                                               \
        _Pragma("unroll")                                                     \
        for (int i = 0; i < 4; ++i) {                                         \
            int b = m0 + wrow + h * 8 + i * 2 + rb_rl;                        \
            vjreg[h * 4 + i] = *reinterpret_cast<const u16x4*>(               \
                wsA + (size_t)b * FD + fj * D_SZ + rb_c * 4);                 \
        }                                                                     \
    f32x4 acc[8];                                                             \
    _Pragma("unroll")                                                         \
    for (int n = 0; n < 8; ++n) acc[n] = (f32x4)0.0f;                         \
    _Pragma("unroll")                                                         \
    for (int n = 0; n < 8; ++n) {                                             \
        int el = n * 16 + lc;                                                 \
        _Pragma("unroll")                                                     \
        for (int kk = 0; kk < 4; ++kk) {                                      \
            bf16x8 wfr = *reinterpret_cast<const bf16x8*>(                    \
                &Ws[CUR][el * 128 + (((kk * 4 + l16) ^ (el & 7)) * 8)]);      \
            acc[n] = __builtin_amdgcn_mfma_f32_16x16x32_bf16(                 \
                wfr, afr[kk], acc[n], 0, 0, 0);                               \
        }                                                                     \
    }                                                                         \
    LGKM_BAR();   /* all waves done reading Ws[CUR]; it becomes scratch */    \
    {                                                                         \
        float* swav = reinterpret_cast<float*>(&Ws[CUR][0]) + wave * 1024;    \
        _Pragma("unroll")                                                     \
        for (int h = 0; h < 2; ++h) {                                         \
            /* dump: half the lanes write their 8 rows of this b-half */      \
            if ((lc >> 3) == h) {                                             \
                int rl = lc & 7;                                              \
                _Pragma("unroll")                                             \
                for (int n = 0; n < 8; ++n) {                                 \
                    int c = n * 4 + l16;                                      \
                    *reinterpret_cast<f32x4*>(                                \
                        &swav[(rl * 32 + (c ^ rl)) * 4]) = acc[n];            \
                }                                                             \
            }                                                                 \
            WAVE_FENCE();   /* dump visible before cross-lane readback */     \
            /* readback: 2 rows x 512B contiguous per instr */                \
            _Pragma("unroll")                                                 \
            for (int i = 0; i < 4; ++i) {                                     \
                int rl = i * 2 + rb_rl;                                       \
                f32x4 v = *reinterpret_cast<const f32x4*>(                    \
                    &swav[(rl * 32 + (rb_c ^ rl)) * 4]);                      \
                int b = m0 + wrow + h * 8 + rl;                               \
                u16x4 vjb = vjreg[h * 4 + i];                                 \
                f32x4 o;                                                      \
                o[0] = v[0] * bf2f(vjb[0]);                                   \
                o[1] = v[1] * bf2f(vjb[1]);                                   \
                o[2] = v[2] * bf2f(vjb[2]);                                   \
                o[3] = v[3] * bf2f(vjb[3]);                                   \
                __builtin_nontemporal_store(o, reinterpret_cast<f32x4*>(      \
                    out + ((size_t)b * P_SZ + p) * D_SZ + rb_c * 4));         \
            }                                                                 \
            WAVE_FENCE();   /* readback done before next-h dump overwrites */ \
        }                                                                     \
    }                                                                         \
    if (has_next) {                                                           \
        if (achg) {                                                           \
            const unsigned short* ar =                                        \
                wsA + (size_t)(m0 + wrow + lc) * FD + fi_n * D_SZ;            \
            _Pragma("unroll")                                                 \
            for (int kk = 0; kk < 4; ++kk)                                    \
                afr[kk] = *reinterpret_cast<const bf16x8*>(                   \
                    ar + (kk * 4 + l16) * 8);                                 \
        }                                                                     \
        /* retire gl_lds+vj (oldest), keep NT stores in flight; lgkm(0) so */ \
        /* every wave's scratch ops are done before next gl_lds lands     */  \
        asm volatile("s_waitcnt vmcnt(8) lgkmcnt(0)" ::: "memory");           \
        __builtin_amdgcn_s_barrier();                                         \
    }                                                                         \
    fi = fi_n; fj = fj_n;                                                     \
} while (0)

    while (true) {
        STEP(0);
        if (++s >= PCH) break;
        STEP(1);
        if (++s >= PCH) break;
    }
#undef STEP
}

extern "C" void kernel_launch(void* const* d_in, const int* in_sizes, int n_in,
                              void* d_out, int out_size, void* d_ws, size_t ws_size,
                              hipStream_t stream) {
    const float* femb = (const float*)d_in[0];
    const float* W    = (const float*)d_in[1];
    float* out        = (float*)d_out;

    unsigned short* wsA = (unsigned short*)d_ws;
    unsigned short* wsW = wsA + FEMB_ELEMS;

    hipLaunchKernelGGL(cvt_bf16_kernel, dim3(2048), dim3(256), 0, stream,
                       femb, wsA, FEMB_ELEMS / 8);
    hipLaunchKernelGGL(cvt_bf16_kernel, dim3(2048), dim3(256), 0, stream,
                       W, wsW, W_ELEMS / 8);
    hipLaunchKernelGGL(bilinear_kernel, dim3(GRID_MAIN), dim3(512), 0, stream,
                       wsA, wsW, out);
}